// Round 1
// baseline (258.624 us; speedup 1.0000x reference)
//
#include <hip/hip_runtime.h>
#include <hip/hip_bf16.h>

// Problem constants: B=16, C=256, H=W=64 (N=4096), NUM_HEADS=8, HD=32, GROUPS=4, EPS=1e-5
// Pipeline:
//  K1  gn_partial:   partial sum/sumsq per (b,g, part)          [1024 blk]
//  K2  finalize:     mu/rstd per (b,g) + qkv_weight fp32->bf16   [193 blk]
//  K3  norm_t:       xnT[b][n][c] = GN(x) as bf16 (transposed)   [4096 blk]
//  K4  gemm_bt:      qT[b][n][d]   = xnT . Wq^T                  (bf16 out)
//  K5  gemm_bt:      kv[b][o][n]   = Wkv . xnT^T                 (bf16 out)
//  K6  att:          att[b,h,d,e] = softmax_n(k) . v^T  (exp-MFMA, fold 1/rowsum)
//  K7  makeM:        M_b[o][h*32+d] = sum_e proj[o][h*32+e] att[h,d,e]  (bf16)
//  K8  gemm_bt:      out[b][o][n] = M_b . qT^T + bias            (f32 out)

typedef __attribute__((ext_vector_type(4))) float f32x4;
typedef __attribute__((ext_vector_type(8))) short bf16x8;
typedef __attribute__((ext_vector_type(4))) short s16x4;
typedef __attribute__((ext_vector_type(8))) unsigned short u16x8;

__device__ inline float b2f(unsigned short u) {
  unsigned int x = ((unsigned int)u) << 16;
  float f; __builtin_memcpy(&f, &x, 4); return f;
}
__device__ inline unsigned short f2b(float f) {
  unsigned int x; __builtin_memcpy(&x, &f, 4);
  x += 0x7FFFu + ((x >> 16) & 1u);            // RNE
  return (unsigned short)(x >> 16);
}

// MFMA 16x16x32 bf16 operand fragment: lane group g=lane>>4, row/col = lane&15.
// k-halves at [4g..4g+3] and [16+4g..16+4g+3]; identical pattern for A and B, so
// any HW k-permutation cancels in the dot product.
__device__ inline bf16x8 make_frag(const unsigned short* rowbase, int g) {
  s16x4 lo = *(const s16x4*)(rowbase + 4 * g);
  s16x4 hi = *(const s16x4*)(rowbase + 16 + 4 * g);
  bf16x8 f;
  f[0] = lo[0]; f[1] = lo[1]; f[2] = lo[2]; f[3] = lo[3];
  f[4] = hi[0]; f[5] = hi[1]; f[6] = hi[2]; f[7] = hi[3];
  return f;
}

// ---------------- K1: GN partial sums ----------------
__global__ void __launch_bounds__(256) k_gn_partial(const float* __restrict__ x,
                                                    float* __restrict__ partials) {
  int blk = blockIdx.x;           // 64 groups * 16 parts
  int grp = blk >> 4;             // b*4+g ; group = 64ch*4096 = 262144 contiguous floats
  int part = blk & 15;
  const float* base = x + (size_t)grp * 262144 + (size_t)part * 16384;
  int t = threadIdx.x;
  float s = 0.f, s2 = 0.f;
  for (int i = 0; i < 16; ++i) {
    f32x4 v = *(const f32x4*)(base + (size_t)(i * 256 + t) * 4);
    s  += v[0] + v[1] + v[2] + v[3];
    s2 += v[0]*v[0] + v[1]*v[1] + v[2]*v[2] + v[3]*v[3];
  }
  for (int o = 32; o > 0; o >>= 1) { s += __shfl_down(s, o); s2 += __shfl_down(s2, o); }
  __shared__ float ls[4], ls2[4];
  int w = t >> 6;
  if ((t & 63) == 0) { ls[w] = s; ls2[w] = s2; }
  __syncthreads();
  if (t == 0) {
    float S = ls[0] + ls[1] + ls[2] + ls[3];
    float S2 = ls2[0] + ls2[1] + ls2[2] + ls2[3];
    partials[blk * 2] = S; partials[blk * 2 + 1] = S2;
  }
}

// ---------------- K2: finalize stats + qkv weight -> bf16 ----------------
__global__ void __launch_bounds__(256) k_finalize(const float* __restrict__ partials,
                                                  float* __restrict__ stats,
                                                  const float* __restrict__ qkvw,
                                                  unsigned short* __restrict__ Wb) {
  if (blockIdx.x == 0) {
    int t = threadIdx.x;
    if (t < 64) {
      float S = 0.f, S2 = 0.f;
      for (int i = 0; i < 16; ++i) { S += partials[(t * 16 + i) * 2]; S2 += partials[(t * 16 + i) * 2 + 1]; }
      float mu = S * (1.f / 262144.f);
      float var = S2 * (1.f / 262144.f) - mu * mu;
      stats[t * 2] = mu;
      stats[t * 2 + 1] = rsqrtf(var + 1e-5f);
    }
  } else {
    int idx = (blockIdx.x - 1) * 256 + threadIdx.x;   // float4 index, 49152 total
    f32x4 v = *(const f32x4*)(qkvw + (size_t)idx * 4);
    s16x4 o;
    for (int i = 0; i < 4; ++i) o[i] = (short)f2b(v[i]);
    *(s16x4*)(Wb + (size_t)idx * 4) = o;
  }
}

// ---------------- K3: GroupNorm apply + transpose -> xnT[b][n][c] bf16 ----------------
__global__ void __launch_bounds__(256) k_norm_t(const float* __restrict__ x,
                                                const float* __restrict__ stats,
                                                const float* __restrict__ gamma,
                                                const float* __restrict__ beta,
                                                unsigned short* __restrict__ xnT) {
  int blk = blockIdx.x;           // 16 b * 256 tiles
  int b = blk >> 8;
  int tile = blk & 255;
  int ct = tile >> 6;             // 0..3  (c-tile == group, since 64ch tiles)
  int nt = tile & 63;             // 0..63
  int c0 = ct * 64, n0 = nt * 64;
  __shared__ float T[64][65];
  int t = threadIdx.x;
  float mu = stats[(b * 4 + ct) * 2];
  float rs = stats[(b * 4 + ct) * 2 + 1];
  int cl = t >> 2, q4 = t & 3;
  float sc = gamma[c0 + cl] * rs;
  float off = beta[c0 + cl] - mu * sc;
  const float* xr = x + ((size_t)b * 256 + c0 + cl) * 4096 + n0;
  for (int p = 0; p < 4; ++p) {
    int col = p * 16 + q4 * 4;
    f32x4 v = *(const f32x4*)(xr + col);
    for (int i = 0; i < 4; ++i) T[cl][col + i] = v[i] * sc + off;
  }
  __syncthreads();
  int nl = t >> 2, cc = t & 3;
  u16x8 o0, o1;
  for (int i = 0; i < 8; ++i) o0[i] = f2b(T[cc * 16 + i][nl]);
  for (int i = 0; i < 8; ++i) o1[i] = f2b(T[cc * 16 + 8 + i][nl]);
  unsigned short* dst = xnT + ((size_t)b * 4096 + n0 + nl) * 256 + c0 + cc * 16;
  *(u16x8*)dst = o0;
  *(u16x8*)(dst + 8) = o1;
}

// ---------------- gemm_bt: C[M][N] = A[M][256] . B[N][256]^T  (bf16 in, fp32 acc) ----------------
template<bool OUT_BF16, bool ADD_BIAS>
__global__ void __launch_bounds__(256)
k_gemm_bt(const unsigned short* __restrict__ A,
          const unsigned short* __restrict__ B,
          void* __restrict__ Cv,
          const float* __restrict__ bias,
          long sA, long sB, long sC, int ldc) {
  __shared__ unsigned short LA[128][40];   // +8 pad: 2-way-free bank pattern on b64 reads
  __shared__ unsigned short LB[128][40];
  const int t = threadIdx.x;
  const int bz = blockIdx.z;
  const unsigned short* Ab = A + (size_t)bz * sA + (size_t)blockIdx.x * 128 * 256;
  const unsigned short* Bb = B + (size_t)bz * sB + (size_t)blockIdx.y * 128 * 256;
  const int wave = t >> 6, lane = t & 63;
  const int wm = wave >> 1, wn = wave & 1;
  const int g = lane >> 4, r = lane & 15;
  const int srow = t >> 1, sq = (t & 1) * 16;
  f32x4 acc[4][4] = {};
  for (int kt = 0; kt < 8; ++kt) {
    const int k0 = kt * 32;
    u16x8 a0 = *(const u16x8*)(Ab + (size_t)srow * 256 + k0 + sq);
    u16x8 a1 = *(const u16x8*)(Ab + (size_t)srow * 256 + k0 + sq + 8);
    u16x8 b0 = *(const u16x8*)(Bb + (size_t)srow * 256 + k0 + sq);
    u16x8 b1 = *(const u16x8*)(Bb + (size_t)srow * 256 + k0 + sq + 8);
    if (kt) __syncthreads();                 // previous iter's frag reads done
    *(u16x8*)&LA[srow][sq] = a0; *(u16x8*)&LA[srow][sq + 8] = a1;
    *(u16x8*)&LB[srow][sq] = b0; *(u16x8*)&LB[srow][sq + 8] = b1;
    __syncthreads();
    bf16x8 af[4], bfr[4];
    for (int i = 0; i < 4; ++i) {
      af[i]  = make_frag(&LA[wm * 64 + i * 16 + r][0], g);
      bfr[i] = make_frag(&LB[wn * 64 + i * 16 + r][0], g);
    }
    for (int mi = 0; mi < 4; ++mi)
      for (int ni = 0; ni < 4; ++ni)
        acc[mi][ni] = __builtin_amdgcn_mfma_f32_16x16x32_bf16(af[mi], bfr[ni], acc[mi][ni], 0, 0, 0);
  }
  const int m0 = blockIdx.x * 128 + wm * 64;
  const int n0 = blockIdx.y * 128 + wn * 64;
  if (OUT_BF16) {
    unsigned short* C = (unsigned short*)Cv + (size_t)bz * sC;
    for (int mi = 0; mi < 4; ++mi)
      for (int ni = 0; ni < 4; ++ni) {
        int row = m0 + mi * 16 + 4 * g;
        int col = n0 + ni * 16 + r;
        for (int reg = 0; reg < 4; ++reg)
          C[(size_t)(row + reg) * ldc + col] = f2b(acc[mi][ni][reg]);
      }
  } else {
    float* C = (float*)Cv + (size_t)bz * sC;
    for (int mi = 0; mi < 4; ++mi)
      for (int ni = 0; ni < 4; ++ni) {
        int row = m0 + mi * 16 + 4 * g;
        int col = n0 + ni * 16 + r;
        for (int reg = 0; reg < 4; ++reg) {
          float v = acc[mi][ni][reg];
          if (ADD_BIAS) v += bias[row + reg];
          C[(size_t)(row + reg) * ldc + col] = v;
        }
      }
  }
}

// ---------------- K6: att[b,h,d,e] = (sum_n exp(k[d,n]) v[e,n]) / rowsum[d] ----------------
__global__ void __launch_bounds__(256) k_att(const unsigned short* __restrict__ kv,
                                             float* __restrict__ attg) {
  int blk = blockIdx.x;           // 16*8
  int b = blk >> 3, h = blk & 7;
  const unsigned short* kbase = kv + ((size_t)b * 512 + h * 32) * 4096;
  const unsigned short* vbase = kbase + (size_t)256 * 4096;
  __shared__ unsigned short P[32][136];
  __shared__ unsigned short V[32][136];
  __shared__ float psum[32][8];
  __shared__ float attbuf[4][32][33];
  __shared__ float invs[32];
  int t = threadIdx.x;
  int d = t >> 3, j = t & 7;
  int wave = t >> 6, lane = t & 63, g = lane >> 4, r = lane & 15;
  float rsum = 0.f;
  f32x4 acc[2][2] = {};
  for (int c = 0; c < 32; ++c) {
    int n0 = c * 128;
    const unsigned short* ksrc = kbase + (size_t)d * 4096 + n0 + j * 16;
    const unsigned short* vsrc = vbase + (size_t)d * 4096 + n0 + j * 16;
    u16x8 ka = *(const u16x8*)ksrc;
    u16x8 kb2 = *(const u16x8*)(ksrc + 8);
    u16x8 va = *(const u16x8*)vsrc;
    u16x8 vb2 = *(const u16x8*)(vsrc + 8);
    u16x8 p0, p1;
    for (int i = 0; i < 8; ++i) { float e = __expf(b2f(ka[i]));  rsum += e; p0[i] = f2b(e); }
    for (int i = 0; i < 8; ++i) { float e = __expf(b2f(kb2[i])); rsum += e; p1[i] = f2b(e); }
    if (c) __syncthreads();
    *(u16x8*)&P[d][j * 16] = p0;     *(u16x8*)&P[d][j * 16 + 8] = p1;
    *(u16x8*)&V[d][j * 16] = va;     *(u16x8*)&V[d][j * 16 + 8] = vb2;
    __syncthreads();
    // each wave covers k-slice [wave*32, wave*32+32) of this 128-chunk
    bf16x8 pf[2], vf[2];
    for (int i = 0; i < 2; ++i) {
      pf[i] = make_frag(&P[i * 16 + r][wave * 32], g);
      vf[i] = make_frag(&V[i * 16 + r][wave * 32], g);
    }
    for (int mi = 0; mi < 2; ++mi)
      for (int ni = 0; ni < 2; ++ni)
        acc[mi][ni] = __builtin_amdgcn_mfma_f32_16x16x32_bf16(pf[mi], vf[ni], acc[mi][ni], 0, 0, 0);
  }
  __syncthreads();
  psum[d][j] = rsum;
  for (int mi = 0; mi < 2; ++mi)
    for (int ni = 0; ni < 2; ++ni)
      for (int reg = 0; reg < 4; ++reg)
        attbuf[wave][mi * 16 + 4 * g + reg][ni * 16 + r] = acc[mi][ni][reg];
  __syncthreads();
  if (t < 32) {
    float s = 0.f;
    for (int i = 0; i < 8; ++i) s += psum[t][i];
    invs[t] = 1.f / s;
  }
  __syncthreads();
  float* dst = attg + (size_t)blk * 1024;
  for (int i = 0; i < 4; ++i) {
    int idx = t * 4 + i;
    int dd = idx >> 5, ee = idx & 31;
    dst[idx] = (attbuf[0][dd][ee] + attbuf[1][dd][ee] + attbuf[2][dd][ee] + attbuf[3][dd][ee]) * invs[dd];
  }
}

// ---------------- K7: M_b[o][h*32+d] = sum_e proj[o][h*32+e] * att[b,h,d,e] ----------------
__global__ void __launch_bounds__(256) k_makeM(const float* __restrict__ attg,
                                               const float* __restrict__ projw,
                                               unsigned short* __restrict__ Mb) {
  int blk = blockIdx.x;           // 16*8
  int b = blk >> 3, h = blk & 7;
  __shared__ float attL[32][33];
  int t = threadIdx.x;
  const float* asrc = attg + (size_t)blk * 1024;
  {
    f32x4 v = *(const f32x4*)(asrc + (size_t)t * 4);
    int idx = t * 4;
    for (int i = 0; i < 4; ++i) attL[(idx + i) >> 5][(idx + i) & 31] = v[i];
  }
  __syncthreads();
  float pw[32];
  const float* ps = projw + (size_t)t * 256 + h * 32;
  for (int i = 0; i < 8; ++i) {
    f32x4 v = *(const f32x4*)(ps + i * 4);
    pw[i * 4 + 0] = v[0]; pw[i * 4 + 1] = v[1]; pw[i * 4 + 2] = v[2]; pw[i * 4 + 3] = v[3];
  }
  unsigned short* dst = Mb + ((size_t)b * 256 + t) * 256 + h * 32;
  for (int dd = 0; dd < 32; ++dd) {
    float s = 0.f;
    for (int e = 0; e < 32; ++e) s += pw[e] * attL[dd][e];
    dst[dd] = f2b(s);
  }
}

extern "C" void kernel_launch(void* const* d_in, const int* in_sizes, int n_in,
                              void* d_out, int out_size, void* d_ws, size_t ws_size,
                              hipStream_t stream) {
  (void)in_sizes; (void)n_in; (void)out_size; (void)ws_size;
  const float* x     = (const float*)d_in[0];
  const float* gn_w  = (const float*)d_in[1];
  const float* gn_b  = (const float*)d_in[2];
  const float* qkvw  = (const float*)d_in[3];
  const float* projw = (const float*)d_in[4];
  const float* projb = (const float*)d_in[5];

  char* ws = (char*)d_ws;
  float*          partials = (float*)(ws);                       //   8 KB
  float*          stats    = (float*)(ws + 8192);                //  512 B
  unsigned short* Wb       = (unsigned short*)(ws + 16384);      //  384 KB (768x256 bf16)
  unsigned short* Mb       = (unsigned short*)(ws + 409600);     //    2 MB (16x256x256 bf16)
  float*          attg     = (float*)(ws + 2506752);             //  512 KB (16x8x32x32 f32)
  unsigned short* xnT      = (unsigned short*)(ws + 4194304);    //   32 MB (16x4096x256 bf16)
  unsigned short* qT       = (unsigned short*)(ws + 4194304 + 33554432);      // 32 MB
  unsigned short* kvb      = (unsigned short*)(ws + 4194304 + 2 * 33554432);  // 64 MB

  k_gn_partial<<<1024, 256, 0, stream>>>(x, partials);
  k_finalize<<<193, 256, 0, stream>>>(partials, stats, qkvw, Wb);
  k_norm_t<<<4096, 256, 0, stream>>>(x, stats, gn_w, gn_b, xnT);
  // qT[b][4096][256] = xnT[b] (4096x256) . Wq(256x256)^T
  k_gemm_bt<true, false><<<dim3(32, 2, 16), 256, 0, stream>>>(
      xnT, Wb, (void*)qT, nullptr, 1048576L, 0L, 1048576L, 256);
  // kv[b][512][4096] = Wkv(512x256) . xnT[b]^T
  k_gemm_bt<true, false><<<dim3(4, 32, 16), 256, 0, stream>>>(
      Wb + 65536, xnT, (void*)kvb, nullptr, 0L, 1048576L, 2097152L, 4096);
  k_att<<<128, 256, 0, stream>>>(kvb, attg);
  k_makeM<<<128, 256, 0, stream>>>(attg, projw, Mb);
  // out[b][256][4096] = M_b(256x256) . qT[b]^T + bias
  k_gemm_bt<false, true><<<dim3(2, 32, 16), 256, 0, stream>>>(
      Mb, qT, d_out, projb, 65536L, 1048576L, 1048576L, 4096);
}

// Round 2
// 241.537 us; speedup vs baseline: 1.0707x; 1.0707x over previous
//
#include <hip/hip_runtime.h>
#include <hip/hip_bf16.h>

// B=16, C=256, H=W=64 (N=4096), HEADS=8, HD=32, GROUPS=4, EPS=1e-5
// Pipeline:
//  K1 gn_partial : partial sum/sumsq per (b,g,part)
//  K2 finalize   : mu/rstd + qkv_weight->bf16 + WqT (bf16 [c][d])
//  K3 norm_t     : xnT[b][n][c] = GN(x) bf16
//  K4 gemm_bt    : kv[b][o][n] = Wkv . xnT^T            (bf16 out)
//  K5 att(x4 nsplit): attg[b,h,d,e] += exp(k).v^T ; rsums += rowsum  (atomic f32)
//  K6 makeM      : P[b][o][hd] = sum_e proj[o][he] attg[h,d,e]/rsum  (bf16)
//  K7 gemm_bt    : M2[b][o][c] = P . WqT^T              (bf16 out)   [= P.Wq]
//  K8 gemm_bt    : out[b][o][n] = M2 . xnT^T + bias     (f32 out)
// Folding: proj@out = P@q = (P@Wq)@xn = M2@xn  — removes the 4096-wide q GEMM.

typedef __attribute__((ext_vector_type(4))) float f32x4;
typedef __attribute__((ext_vector_type(8))) short bf16x8;
typedef __attribute__((ext_vector_type(4))) short s16x4;
typedef __attribute__((ext_vector_type(8))) unsigned short u16x8;

__device__ inline float b2f(unsigned short u) {
  unsigned int x = ((unsigned int)u) << 16;
  float f; __builtin_memcpy(&f, &x, 4); return f;
}
__device__ inline unsigned short f2b(float f) {
  unsigned int x; __builtin_memcpy(&x, &f, 4);
  x += 0x7FFFu + ((x >> 16) & 1u);            // RNE
  return (unsigned short)(x >> 16);
}

// ---------------- K1: GN partial sums ----------------
__global__ void __launch_bounds__(256) k_gn_partial(const float* __restrict__ x,
                                                    float* __restrict__ partials) {
  int blk = blockIdx.x;           // 64 groups * 16 parts
  int grp = blk >> 4;
  int part = blk & 15;
  const float* base = x + (size_t)grp * 262144 + (size_t)part * 16384;
  int t = threadIdx.x;
  float s = 0.f, s2 = 0.f;
  for (int i = 0; i < 16; ++i) {
    f32x4 v = *(const f32x4*)(base + (size_t)(i * 256 + t) * 4);
    s  += v[0] + v[1] + v[2] + v[3];
    s2 += v[0]*v[0] + v[1]*v[1] + v[2]*v[2] + v[3]*v[3];
  }
  for (int o = 32; o > 0; o >>= 1) { s += __shfl_down(s, o); s2 += __shfl_down(s2, o); }
  __shared__ float ls[4], ls2[4];
  int w = t >> 6;
  if ((t & 63) == 0) { ls[w] = s; ls2[w] = s2; }
  __syncthreads();
  if (t == 0) {
    partials[blk * 2] = ls[0] + ls[1] + ls[2] + ls[3];
    partials[blk * 2 + 1] = ls2[0] + ls2[1] + ls2[2] + ls2[3];
  }
}

// ---------------- K2: finalize stats + qkv weight -> bf16 + WqT ----------------
__global__ void __launch_bounds__(256) k_finalize(const float* __restrict__ partials,
                                                  float* __restrict__ stats,
                                                  const float* __restrict__ qkvw,
                                                  unsigned short* __restrict__ Wb,
                                                  unsigned short* __restrict__ WqT) {
  int bx = blockIdx.x, t = threadIdx.x;
  if (bx == 0) {
    if (t < 64) {
      float S = 0.f, S2 = 0.f;
      for (int i = 0; i < 16; ++i) { S += partials[(t * 16 + i) * 2]; S2 += partials[(t * 16 + i) * 2 + 1]; }
      float mu = S * (1.f / 262144.f);
      float var = S2 * (1.f / 262144.f) - mu * mu;
      stats[t * 2] = mu;
      stats[t * 2 + 1] = rsqrtf(var + 1e-5f);
    }
  } else if (bx <= 192) {
    int idx = (bx - 1) * 256 + t;               // float4 index, 49152 total
    f32x4 v = *(const f32x4*)(qkvw + (size_t)idx * 4);
    s16x4 o;
    for (int i = 0; i < 4; ++i) o[i] = (short)f2b(v[i]);
    *(s16x4*)(Wb + (size_t)idx * 4) = o;
  } else {
    // WqT[c][d] = qkvw[d][c], bf16, 256x256.  16 blocks (193..208).
    int bb = bx - 193;
    int c = bb * 16 + (t & 15);
    int d0 = (t >> 4) * 16;
    for (int i = 0; i < 16; ++i) {
      int d = d0 + i;
      WqT[(size_t)c * 256 + d] = f2b(qkvw[(size_t)d * 256 + c]);
    }
  }
}

// ---------------- K3: GroupNorm apply + transpose -> xnT[b][n][c] bf16 ----------------
__global__ void __launch_bounds__(256) k_norm_t(const float* __restrict__ x,
                                                const float* __restrict__ stats,
                                                const float* __restrict__ gamma,
                                                const float* __restrict__ beta,
                                                unsigned short* __restrict__ xnT) {
  int blk = blockIdx.x;           // 16 b * 256 tiles
  int b = blk >> 8;
  int tile = blk & 255;
  int ct = tile >> 6;
  int nt = tile & 63;
  int c0 = ct * 64, n0 = nt * 64;
  __shared__ float T[64][65];
  int t = threadIdx.x;
  float mu = stats[(b * 4 + ct) * 2];
  float rs = stats[(b * 4 + ct) * 2 + 1];
  int cl = t >> 2, q4 = t & 3;
  float sc = gamma[c0 + cl] * rs;
  float off = beta[c0 + cl] - mu * sc;
  const float* xr = x + ((size_t)b * 256 + c0 + cl) * 4096 + n0;
  for (int p = 0; p < 4; ++p) {
    int col = p * 16 + q4 * 4;
    f32x4 v = *(const f32x4*)(xr + col);
    for (int i = 0; i < 4; ++i) T[cl][col + i] = v[i] * sc + off;
  }
  __syncthreads();
  int nl = t >> 2, cc = t & 3;
  u16x8 o0, o1;
  for (int i = 0; i < 8; ++i) o0[i] = f2b(T[cc * 16 + i][nl]);
  for (int i = 0; i < 8; ++i) o1[i] = f2b(T[cc * 16 + 8 + i][nl]);
  unsigned short* dst = xnT + ((size_t)b * 4096 + n0 + nl) * 256 + c0 + cc * 16;
  *(u16x8*)dst = o0;
  *(u16x8*)(dst + 8) = o1;
}

// ---------------- gemm_bt: C[M][N] = A[M][256] . B[N][256]^T (bf16 in, f32 acc) ----------
// XOR-swizzled [128][32] LDS (slot' = slot ^ (row&3)), single ds_read_b128 frags
// (k-permutation identical on A and B => cancels), distance-1 register prefetch.
template<bool OUT_BF16, bool ADD_BIAS>
__global__ void __launch_bounds__(256)
k_gemm_bt(const unsigned short* __restrict__ A,
          const unsigned short* __restrict__ B,
          void* __restrict__ Cv,
          const float* __restrict__ bias,
          long sA, long sB, long sC, int ldc) {
  __shared__ unsigned short LA[128][32];
  __shared__ unsigned short LB[128][32];
  const int t = threadIdx.x;
  const unsigned short* Ab = A + (size_t)blockIdx.z * sA + (size_t)blockIdx.x * 128 * 256;
  const unsigned short* Bb = B + (size_t)blockIdx.z * sB + (size_t)blockIdx.y * 128 * 256;
  const int wave = t >> 6, lane = t & 63;
  const int wm = wave >> 1, wn = wave & 1;
  const int g = lane >> 4, r = lane & 15;
  const int rA = t >> 2, sslot = t & 3;          // stage rows rA, rA+64; 16B slot sslot
  const int ws0 = 8 * (sslot ^ (rA & 3));        // phys slot (shorts); (rA+64)&3 == rA&3
  const int rslot = 8 * (g ^ (r & 3));           // read slot for frag rows (&3 == r&3)
  const unsigned short* ag = Ab + (size_t)rA * 256 + 8 * sslot;
  const unsigned short* bg = Bb + (size_t)rA * 256 + 8 * sslot;
  u16x8 pa0 = *(const u16x8*)(ag);
  u16x8 pa1 = *(const u16x8*)(ag + 64 * 256);
  u16x8 pb0 = *(const u16x8*)(bg);
  u16x8 pb1 = *(const u16x8*)(bg + 64 * 256);
  f32x4 acc[4][4] = {};
  for (int kt = 0; kt < 8; ++kt) {
    if (kt) __syncthreads();                     // all frag reads of kt-1 done
    *(u16x8*)&LA[rA][ws0] = pa0;  *(u16x8*)&LA[rA + 64][ws0] = pa1;
    *(u16x8*)&LB[rA][ws0] = pb0;  *(u16x8*)&LB[rA + 64][ws0] = pb1;
    __syncthreads();
    if (kt < 7) {                                // prefetch kt+1, overlaps ds_read+MFMA
      int off = (kt + 1) * 32;
      pa0 = *(const u16x8*)(ag + off);  pa1 = *(const u16x8*)(ag + 64 * 256 + off);
      pb0 = *(const u16x8*)(bg + off);  pb1 = *(const u16x8*)(bg + 64 * 256 + off);
    }
    bf16x8 af[4], bfr[4];
    for (int i = 0; i < 4; ++i) {
      af[i]  = *(const bf16x8*)&LA[wm * 64 + i * 16 + r][rslot];
      bfr[i] = *(const bf16x8*)&LB[wn * 64 + i * 16 + r][rslot];
    }
    for (int mi = 0; mi < 4; ++mi)
      for (int ni = 0; ni < 4; ++ni)
        acc[mi][ni] = __builtin_amdgcn_mfma_f32_16x16x32_bf16(af[mi], bfr[ni], acc[mi][ni], 0, 0, 0);
  }
  const int m0 = blockIdx.x * 128 + wm * 64;
  const int n0 = blockIdx.y * 128 + wn * 64;
  if (OUT_BF16) {
    unsigned short* C = (unsigned short*)Cv + (size_t)blockIdx.z * sC;
    for (int mi = 0; mi < 4; ++mi)
      for (int ni = 0; ni < 4; ++ni) {
        int row = m0 + mi * 16 + 4 * g;
        int col = n0 + ni * 16 + r;
        for (int reg = 0; reg < 4; ++reg)
          C[(size_t)(row + reg) * ldc + col] = f2b(acc[mi][ni][reg]);
      }
  } else {
    float* C = (float*)Cv + (size_t)blockIdx.z * sC;
    for (int mi = 0; mi < 4; ++mi)
      for (int ni = 0; ni < 4; ++ni) {
        int row = m0 + mi * 16 + 4 * g;
        int col = n0 + ni * 16 + r;
        for (int reg = 0; reg < 4; ++reg) {
          float v = acc[mi][ni][reg];
          if (ADD_BIAS) v += bias[row + reg];
          C[(size_t)(row + reg) * ldc + col] = v;
        }
      }
  }
}

// ---------------- K5: partial att over n-slice; atomic accumulate ----------------
__global__ void __launch_bounds__(256) k_att(const unsigned short* __restrict__ kv,
                                             float* __restrict__ attg,
                                             float* __restrict__ rsums) {
  int ns = blockIdx.x, h = blockIdx.y, b = blockIdx.z;
  int hb = b * 8 + h;
  const unsigned short* kbase = kv + ((size_t)b * 512 + h * 32) * 4096 + ns * 1024;
  const unsigned short* vbase = kbase + (size_t)256 * 4096;
  __shared__ unsigned short P[32][136];
  __shared__ unsigned short V[32][136];
  __shared__ float psum[32][8];
  __shared__ float attbuf[4][32][33];
  int t = threadIdx.x;
  int d = t >> 3, j = t & 7;
  int wave = t >> 6, lane = t & 63, g = lane >> 4, r = lane & 15;
  float rsum = 0.f;
  f32x4 acc[2][2] = {};
  for (int c = 0; c < 8; ++c) {
    int n0 = c * 128;
    const unsigned short* ksrc = kbase + (size_t)d * 4096 + n0 + j * 16;
    const unsigned short* vsrc = vbase + (size_t)d * 4096 + n0 + j * 16;
    u16x8 ka = *(const u16x8*)ksrc;
    u16x8 kb2 = *(const u16x8*)(ksrc + 8);
    u16x8 va = *(const u16x8*)vsrc;
    u16x8 vb2 = *(const u16x8*)(vsrc + 8);
    u16x8 p0, p1;
    for (int i = 0; i < 8; ++i) { float e = __expf(b2f(ka[i]));  rsum += e; p0[i] = f2b(e); }
    for (int i = 0; i < 8; ++i) { float e = __expf(b2f(kb2[i])); rsum += e; p1[i] = f2b(e); }
    if (c) __syncthreads();
    *(u16x8*)&P[d][j * 16] = p0;     *(u16x8*)&P[d][j * 16 + 8] = p1;
    *(u16x8*)&V[d][j * 16] = va;     *(u16x8*)&V[d][j * 16 + 8] = vb2;
    __syncthreads();
    bf16x8 pf[2], vf[2];
    for (int i = 0; i < 2; ++i) {
      pf[i] = *(const bf16x8*)&P[i * 16 + r][wave * 32 + 8 * g];
      vf[i] = *(const bf16x8*)&V[i * 16 + r][wave * 32 + 8 * g];
    }
    for (int mi = 0; mi < 2; ++mi)
      for (int ni = 0; ni < 2; ++ni)
        acc[mi][ni] = __builtin_amdgcn_mfma_f32_16x16x32_bf16(pf[mi], vf[ni], acc[mi][ni], 0, 0, 0);
  }
  __syncthreads();
  psum[d][j] = rsum;
  for (int mi = 0; mi < 2; ++mi)
    for (int ni = 0; ni < 2; ++ni)
      for (int reg = 0; reg < 4; ++reg)
        attbuf[wave][mi * 16 + 4 * g + reg][ni * 16 + r] = acc[mi][ni][reg];
  __syncthreads();
  if (t < 32) {
    float s = 0.f;
    for (int i = 0; i < 8; ++i) s += psum[t][i];
    atomicAdd(&rsums[hb * 32 + t], s);
  }
  float* dst = attg + (size_t)hb * 1024;
  for (int i = 0; i < 4; ++i) {
    int idx = t * 4 + i;
    int dd = idx >> 5, ee = idx & 31;
    atomicAdd(&dst[idx],
              attbuf[0][dd][ee] + attbuf[1][dd][ee] + attbuf[2][dd][ee] + attbuf[3][dd][ee]);
  }
}

// ---------------- K6: P[b][o][hd] = sum_e proj[o][he] * attg[h,d,e]/rsum[d] ----------------
__global__ void __launch_bounds__(256) k_makeM(const float* __restrict__ attg,
                                               const float* __restrict__ rsums,
                                               const float* __restrict__ projw,
                                               unsigned short* __restrict__ Mb) {
  int blk = blockIdx.x;           // 16*8 (b,h)
  int b = blk >> 3, h = blk & 7;
  __shared__ float attL[32][33];
  __shared__ float invs[32];
  int t = threadIdx.x;
  if (t < 32) invs[t] = 1.f / rsums[blk * 32 + t];
  const float* asrc = attg + (size_t)blk * 1024;
  {
    f32x4 v = *(const f32x4*)(asrc + (size_t)t * 4);
    int idx = t * 4;
    for (int i = 0; i < 4; ++i) attL[(idx + i) >> 5][(idx + i) & 31] = v[i];
  }
  __syncthreads();
  float pw[32];
  const float* ps = projw + (size_t)t * 256 + h * 32;
  for (int i = 0; i < 8; ++i) {
    f32x4 v = *(const f32x4*)(ps + i * 4);
    pw[i * 4 + 0] = v[0]; pw[i * 4 + 1] = v[1]; pw[i * 4 + 2] = v[2]; pw[i * 4 + 3] = v[3];
  }
  unsigned short* dst = Mb + ((size_t)b * 256 + t) * 256 + h * 32;
  for (int dd = 0; dd < 32; ++dd) {
    float s = 0.f;
    for (int e = 0; e < 32; ++e) s += pw[e] * attL[dd][e];
    dst[dd] = f2b(s * invs[dd]);
  }
}

extern "C" void kernel_launch(void* const* d_in, const int* in_sizes, int n_in,
                              void* d_out, int out_size, void* d_ws, size_t ws_size,
                              hipStream_t stream) {
  (void)in_sizes; (void)n_in; (void)out_size; (void)ws_size;
  const float* x     = (const float*)d_in[0];
  const float* gn_w  = (const float*)d_in[1];
  const float* gn_b  = (const float*)d_in[2];
  const float* qkvw  = (const float*)d_in[3];
  const float* projw = (const float*)d_in[4];
  const float* projb = (const float*)d_in[5];

  char* ws = (char*)d_ws;
  float*          partials = (float*)(ws);                       //   8 KB
  float*          stats    = (float*)(ws + 8192);                //  512 B
  unsigned short* Wb       = (unsigned short*)(ws + 16384);      //  384 KB (768x256)
  unsigned short* Mb       = (unsigned short*)(ws + 409600);     //    2 MB (P: 16x256x256)
  float*          attg     = (float*)(ws + 2506752);             //  512 KB (16x8x32x32)
  float*          rsums    = (float*)(ws + 3031040);             //   16 KB (16x8x32)
  unsigned short* WqT      = (unsigned short*)(ws + 3047424);    //  128 KB (256x256)
  unsigned short* M2       = (unsigned short*)(ws + 3178496);    //    2 MB (16x256x256)
  unsigned short* xnT      = (unsigned short*)(ws + 8388608);    //   32 MB (16x4096x256)
  unsigned short* kvb      = (unsigned short*)(ws + 8388608 + 33554432);  // 64 MB

  k_gn_partial<<<1024, 256, 0, stream>>>(x, partials);
  k_finalize<<<209, 256, 0, stream>>>(partials, stats, qkvw, Wb, WqT);
  k_norm_t<<<4096, 256, 0, stream>>>(x, stats, gn_w, gn_b, xnT);
  // kv[b][512][4096] = Wkv(512x256) . xnT[b]^T
  k_gemm_bt<true, false><<<dim3(4, 32, 16), 256, 0, stream>>>(
      Wb + 65536, xnT, (void*)kvb, nullptr, 0L, 1048576L, 2097152L, 4096);
  hipMemsetAsync(attg, 0, 540672, stream);   // attg + rsums (contiguous)
  k_att<<<dim3(4, 8, 16), 256, 0, stream>>>(kvb, attg, rsums);
  k_makeM<<<128, 256, 0, stream>>>(attg, rsums, projw, Mb);
  // M2[b][256][256] = P . WqT^T  (= P . Wq)
  k_gemm_bt<true, false><<<dim3(2, 2, 16), 256, 0, stream>>>(
      Mb, WqT, (void*)M2, nullptr, 65536L, 0L, 65536L, 256);
  // out[b][256][4096] = M2 . xnT^T + bias
  k_gemm_bt<false, true><<<dim3(2, 32, 16), 256, 0, stream>>>(
      M2, xnT, d_out, projb, 65536L, 1048576L, 1048576L, 4096);
}